// Round 1
// baseline (645.725 us; speedup 1.0000x reference)
//
#include <hip/hip_runtime.h>
#include <stdint.h>

#define B_    64
#define CIN   64
#define L_IN  16384
#define COUT  128
#define K_    7
#define LPAD  3
#define LP    (L_IN + 2*LPAD)   // 16390 packed positions per (b)
#define LPA   16416             // padded row stride for A
#define LOUT  8189              // pooled output length
#define NTERMS 448
#define TOUT  8                 // pooled outputs per thread

// ---------------- pack A: sign bits of I along Cin into uint64 ----------------
// A[b][l]: bit ci = 1 iff value < 0. Pad positions (value -1.0) = all ones.
__global__ __launch_bounds__(256) void pack_A(const float* __restrict__ I,
                                              uint64_t* __restrict__ A) {
    int b     = blockIdx.x >> 4;     // 16 blocks per b
    int chunk = blockIdx.x & 15;
    int t     = threadIdx.x;
    int l0    = chunk * 1024 + t * 4;
    const uint32_t* Ib = (const uint32_t*)(I + (size_t)b * CIN * L_IN + l0);
    uint32_t lo0 = 0, lo1 = 0, lo2 = 0, lo3 = 0;
    uint32_t hi0 = 0, hi1 = 0, hi2 = 0, hi3 = 0;
#pragma unroll 8
    for (int ci = 0; ci < 32; ++ci) {
        uint4 v = *(const uint4*)(Ib + (size_t)ci * L_IN);
        lo0 |= (v.x >> 31) << ci;
        lo1 |= (v.y >> 31) << ci;
        lo2 |= (v.z >> 31) << ci;
        lo3 |= (v.w >> 31) << ci;
    }
#pragma unroll 8
    for (int ci = 0; ci < 32; ++ci) {
        uint4 v = *(const uint4*)(Ib + (size_t)(ci + 32) * L_IN);
        hi0 |= (v.x >> 31) << ci;
        hi1 |= (v.y >> 31) << ci;
        hi2 |= (v.z >> 31) << ci;
        hi3 |= (v.w >> 31) << ci;
    }
    uint64_t* Ab = A + (size_t)b * LPA + (LPAD + l0);
    Ab[0] = ((uint64_t)hi0 << 32) | lo0;
    Ab[1] = ((uint64_t)hi1 << 32) | lo1;
    Ab[2] = ((uint64_t)hi2 << 32) | lo2;
    Ab[3] = ((uint64_t)hi3 << 32) | lo3;
    // pad columns: l in {0,1,2, 16387,16388,16389} -> sign(-1.0) -> all ones
    if (chunk == 0 && t < 6) {
        int l = (t < 3) ? t : (L_IN + t);
        A[(size_t)b * LPA + l] = ~0ULL;
    }
}

// ---------------- pack W ----------------
__global__ __launch_bounds__(256) void pack_W(const float* __restrict__ W,
                                              uint64_t* __restrict__ Bp) {
    int idx = blockIdx.x * 256 + threadIdx.x;
    if (idx >= COUT * K_) return;
    int co = idx / K_, k = idx - co * K_;
    uint64_t acc = 0;
#pragma unroll
    for (int ci = 0; ci < CIN; ++ci) {
        uint32_t s = __float_as_uint(W[(size_t)co * CIN * K_ + ci * K_ + k]) >> 31;
        acc |= (uint64_t)s << ci;
    }
    Bp[idx] = acc;
}

// ---------------- main: binary conv + maxpool(7,2) + threshold ----------------
// One co per block: a[27] has a single short live range -> stays register-resident
// (the 16-deep co-loop version was demoted to L1 reloads: VGPR_Count=40).
__global__ __launch_bounds__(256, 4) void bconv_pool_thresh(
    const uint64_t* __restrict__ A, const uint64_t* __restrict__ Bp,
    const float* __restrict__ tp_, const float* __restrict__ tm_,
    const float* __restrict__ ps_, const float* __restrict__ ms_,
    float* __restrict__ out)
{
    const int co = blockIdx.x;   // 0..127
    const int lc = blockIdx.y;   // 0..3   l chunk
    const int b  = blockIdx.z;   // 0..63
    const int t  = threadIdx.x;
    int out0 = lc * 2048 + t * TOUT;
    // clamp so every lane writes TOUT valid outputs (duplicates write identical values)
    if (out0 > LOUT - TOUT) out0 = LOUT - TOUT;

    // A window: conv positions [2*out0 .. 2*out0+20], each uses a[j..j+6] -> 27 words
    const uint64_t* Ab = A + (size_t)b * LPA + 2 * out0;   // even word index -> 16B aligned
    uint64_t a[2 * TOUT + 11];
#pragma unroll
    for (int j = 0; j < 13; ++j) {
        ulonglong2 v = *(const ulonglong2*)(Ab + 2 * j);
        a[2 * j]     = v.x;
        a[2 * j + 1] = v.y;
    }
    a[26] = Ab[26];

    // w is wave-uniform -> scalar loads; v_xor with SGPR operand is free
    const uint64_t* Bco = Bp + co * K_;
    const uint64_t w0 = Bco[0], w1 = Bco[1], w2 = Bco[2], w3 = Bco[3],
                   w4 = Bco[4], w5 = Bco[5], w6 = Bco[6];

    // s[j] = sum_k popcount(a[j+k] ^ w[k]);  conv = 448 - 2*s
    int s[2 * TOUT + 5];
#pragma unroll
    for (int j = 0; j < 2 * TOUT + 5; ++j) {
        int acc;
        acc  = __popcll(a[j + 0] ^ w0);
        acc += __popcll(a[j + 1] ^ w1);
        acc += __popcll(a[j + 2] ^ w2);
        acc += __popcll(a[j + 3] ^ w3);
        acc += __popcll(a[j + 4] ^ w4);
        acc += __popcll(a[j + 5] ^ w5);
        acc += __popcll(a[j + 6] ^ w6);
        s[j] = acc;
    }

    int p[TOUT + 2];
#pragma unroll
    for (int i = 0; i < TOUT + 2; ++i) p[i] = min(s[2 * i], s[2 * i + 1]);

    // epilogue in s-domain: pooled = 448-2*smin; pooled>tp <=> smin < (448-tp)/2
    const float ftp = (448.0f - tp_[co]) * 0.5f;
    const float ftm = (448.0f - tm_[co]) * 0.5f;
    const float ps = ps_[co], ms = ms_[co];
    float* op = out + ((size_t)(b * COUT + co)) * LOUT + out0;
#pragma unroll
    for (int o = 0; o < TOUT; ++o) {
        int smin = min(min(p[o], p[o + 1]), min(p[o + 2], s[2 * o + 6]));
        float sf  = (float)smin;
        float pos = sf < ftp ? ps : -ps;
        float neg = sf < ftm ? ms : -ms;
        // streamed 268 MB output, never re-read: keep it out of L2 so the
        // shared A-window stays resident
        __builtin_nontemporal_store((sf <= 224.0f) ? pos : neg, op + o);
    }
}

extern "C" void kernel_launch(void* const* d_in, const int* in_sizes, int n_in,
                              void* d_out, int out_size, void* d_ws, size_t ws_size,
                              hipStream_t stream) {
    const float* I  = (const float*)d_in[0];
    const float* W  = (const float*)d_in[1];
    const float* tp = (const float*)d_in[2];
    const float* tm = (const float*)d_in[3];
    const float* ps = (const float*)d_in[4];
    const float* ms = (const float*)d_in[5];
    float* out = (float*)d_out;

    uint64_t* A  = (uint64_t*)d_ws;
    uint64_t* Bp = (uint64_t*)((char*)d_ws + (size_t)B_ * LPA * sizeof(uint64_t));

    hipLaunchKernelGGL(pack_A, dim3(B_ * 16), dim3(256), 0, stream, I, A);
    hipLaunchKernelGGL(pack_W, dim3((COUT * K_ + 255) / 256), dim3(256), 0, stream, W, Bp);
    hipLaunchKernelGGL(bconv_pool_thresh, dim3(COUT, 4, B_), dim3(256), 0, stream,
                       A, Bp, tp, tm, ps, ms, out);
}

// Round 2
// 631.969 us; speedup vs baseline: 1.0218x; 1.0218x over previous
//
#include <hip/hip_runtime.h>
#include <stdint.h>

#define B_    64
#define CIN   64
#define L_IN  16384
#define COUT  128
#define K_    7
#define LPAD  3
#define LP    (L_IN + 2*LPAD)   // 16390 packed positions per (b)
#define LPA   16416             // padded row stride for A
#define LOUT  8189              // pooled output length
#define NTERMS 448
#define TOUT  16                // pooled outputs per thread (21->37 conv pos: -12% core work)

// ---------------- pack A: sign bits of I along Cin into uint64 ----------------
// A[b][l]: bit ci = 1 iff value < 0. Pad positions (value -1.0) = all ones.
__global__ __launch_bounds__(256) void pack_A(const float* __restrict__ I,
                                              uint64_t* __restrict__ A) {
    int b     = blockIdx.x >> 4;     // 16 blocks per b
    int chunk = blockIdx.x & 15;
    int t     = threadIdx.x;
    int l0    = chunk * 1024 + t * 4;
    const uint32_t* Ib = (const uint32_t*)(I + (size_t)b * CIN * L_IN + l0);
    uint32_t lo0 = 0, lo1 = 0, lo2 = 0, lo3 = 0;
    uint32_t hi0 = 0, hi1 = 0, hi2 = 0, hi3 = 0;
#pragma unroll 8
    for (int ci = 0; ci < 32; ++ci) {
        uint4 v = *(const uint4*)(Ib + (size_t)ci * L_IN);
        lo0 |= (v.x >> 31) << ci;
        lo1 |= (v.y >> 31) << ci;
        lo2 |= (v.z >> 31) << ci;
        lo3 |= (v.w >> 31) << ci;
    }
#pragma unroll 8
    for (int ci = 0; ci < 32; ++ci) {
        uint4 v = *(const uint4*)(Ib + (size_t)(ci + 32) * L_IN);
        hi0 |= (v.x >> 31) << ci;
        hi1 |= (v.y >> 31) << ci;
        hi2 |= (v.z >> 31) << ci;
        hi3 |= (v.w >> 31) << ci;
    }
    uint64_t* Ab = A + (size_t)b * LPA + (LPAD + l0);
    Ab[0] = ((uint64_t)hi0 << 32) | lo0;
    Ab[1] = ((uint64_t)hi1 << 32) | lo1;
    Ab[2] = ((uint64_t)hi2 << 32) | lo2;
    Ab[3] = ((uint64_t)hi3 << 32) | lo3;
    // pad columns: l in {0,1,2, 16387,16388,16389} -> sign(-1.0) -> all ones
    if (chunk == 0 && t < 6) {
        int l = (t < 3) ? t : (L_IN + t);
        A[(size_t)b * LPA + l] = ~0ULL;
    }
}

// ---------------- pack W ----------------
__global__ __launch_bounds__(256) void pack_W(const float* __restrict__ W,
                                              uint64_t* __restrict__ Bp) {
    int idx = blockIdx.x * 256 + threadIdx.x;
    if (idx >= COUT * K_) return;
    int co = idx / K_, k = idx - co * K_;
    uint64_t acc = 0;
#pragma unroll
    for (int ci = 0; ci < CIN; ++ci) {
        uint32_t s = __float_as_uint(W[(size_t)co * CIN * K_ + ci * K_ + k]) >> 31;
        acc |= (uint64_t)s << ci;
    }
    Bp[idx] = acc;
}

// ---------------- main: binary conv + maxpool(7,2) + threshold ----------------
// One co per block (best occupancy, A re-reads are L2/L3-absorbed: FETCH ~33MB).
// TOUT=16: 37 conv positions per 16 outputs = 2.31 conv/output (vs 2.625 at TOUT=8).
// Epilogue fully integer-domain: precomputed Tp/Tm, no per-output v_cvt.
__global__ __launch_bounds__(256, 4) void bconv_pool_thresh(
    const uint64_t* __restrict__ A, const uint64_t* __restrict__ Bp,
    const float* __restrict__ tp_, const float* __restrict__ tm_,
    const float* __restrict__ ps_, const float* __restrict__ ms_,
    float* __restrict__ out)
{
    const int co = blockIdx.x;   // 0..127
    const int lc = blockIdx.y;   // 0..1   l chunk (2 x 4096 outputs covers 8189)
    const int b  = blockIdx.z;   // 0..63
    const int t  = threadIdx.x;
    int out0 = lc * 4096 + t * TOUT;
    // clamp so every lane writes TOUT valid outputs (duplicates write identical values)
    if (out0 > LOUT - TOUT) out0 = LOUT - TOUT;

    // A window: conv positions [2*out0 .. 2*out0+2*TOUT+4], each uses a[j..j+6]
    const uint64_t* Ab = A + (size_t)b * LPA + 2 * out0;   // even word index -> 16B aligned
    uint64_t a[2 * TOUT + 11];
#pragma unroll
    for (int j = 0; j < TOUT + 5; ++j) {               // 21 x 16B loads
        ulonglong2 v = *(const ulonglong2*)(Ab + 2 * j);
        a[2 * j]     = v.x;
        a[2 * j + 1] = v.y;
    }
    a[2 * TOUT + 10] = Ab[2 * TOUT + 10];

    // w is wave-uniform -> scalar loads; v_xor with SGPR operand is free
    const uint64_t* Bco = Bp + co * K_;
    const uint64_t w0 = Bco[0], w1 = Bco[1], w2 = Bco[2], w3 = Bco[3],
                   w4 = Bco[4], w5 = Bco[5], w6 = Bco[6];

    // s[j] = sum_k popcount(a[j+k] ^ w[k]);  conv = 448 - 2*s
    int s[2 * TOUT + 5];
#pragma unroll
    for (int j = 0; j < 2 * TOUT + 5; ++j) {
        int acc;
        acc  = __popcll(a[j + 0] ^ w0);
        acc += __popcll(a[j + 1] ^ w1);
        acc += __popcll(a[j + 2] ^ w2);
        acc += __popcll(a[j + 3] ^ w3);
        acc += __popcll(a[j + 4] ^ w4);
        acc += __popcll(a[j + 5] ^ w5);
        acc += __popcll(a[j + 6] ^ w6);
        s[j] = acc;
    }

    int p[TOUT + 2];
#pragma unroll
    for (int i = 0; i < TOUT + 2; ++i) p[i] = min(s[2 * i], s[2 * i + 1]);

    // epilogue in s-domain (integer): pooled = 448-2*smin
    //   pooled > tp  <=>  smin < (448-tp)/2  <=>  smin <= ceil((448-tp)/2)-1
    //   pooled >= 0  <=>  smin <= 224
    const int Tp = (int)ceilf((448.0f - tp_[co]) * 0.5f) - 1;
    const int Tm = (int)ceilf((448.0f - tm_[co]) * 0.5f) - 1;
    const float ps = ps_[co], ms = ms_[co];
    float* op = out + ((size_t)(b * COUT + co)) * LOUT + out0;
#pragma unroll
    for (int o = 0; o < TOUT; ++o) {
        int smin = min(min(p[o], p[o + 1]), min(p[o + 2], s[2 * o + 6]));
        float pos = smin <= Tp ? ps : -ps;
        float neg = smin <= Tm ? ms : -ms;
        op[o] = (smin <= 224) ? pos : neg;
    }
}

extern "C" void kernel_launch(void* const* d_in, const int* in_sizes, int n_in,
                              void* d_out, int out_size, void* d_ws, size_t ws_size,
                              hipStream_t stream) {
    const float* I  = (const float*)d_in[0];
    const float* W  = (const float*)d_in[1];
    const float* tp = (const float*)d_in[2];
    const float* tm = (const float*)d_in[3];
    const float* ps = (const float*)d_in[4];
    const float* ms = (const float*)d_in[5];
    float* out = (float*)d_out;

    uint64_t* A  = (uint64_t*)d_ws;
    uint64_t* Bp = (uint64_t*)((char*)d_ws + (size_t)B_ * LPA * sizeof(uint64_t));

    hipLaunchKernelGGL(pack_A, dim3(B_ * 16), dim3(256), 0, stream, I, A);
    hipLaunchKernelGGL(pack_W, dim3((COUT * K_ + 255) / 256), dim3(256), 0, stream, W, Bp);
    hipLaunchKernelGGL(bconv_pool_thresh, dim3(COUT, 2, B_), dim3(256), 0, stream,
                       A, Bp, tp, tm, ps, ms, out);
}